// Round 7
// baseline (314.511 us; speedup 1.0000x reference)
//
#include <hip/hip_runtime.h>
#include <cstdint>

typedef float    f32x4 __attribute__((ext_vector_type(4)));
typedef _Float16 f16x8 __attribute__((ext_vector_type(8)));
typedef unsigned int uint32;

// ---------------------------------------------------------------------------
// Workspace (ushort units): two fp16[256][256] arrays (RNE, alpha folded in)
//   [0]      Wn[i][j] = f16(0.5*W[i][j])   (A-operand for Xv update)
//   [65536]  Wt[j][i] = f16(0.5*W[i][j])   (A-operand for Xh update)
// ---------------------------------------------------------------------------

__global__ void HAM_prep_w(const float* __restrict__ W, unsigned short* __restrict__ ws)
{
    int idx = blockIdx.x * 256 + threadIdx.x;          // 0 .. 65535
    int i = idx >> 8, j = idx & 255;
    _Float16 h = (_Float16)(0.5f * W[idx]);            // RNE, rel err <= 2^-12
    unsigned short hb = __builtin_bit_cast(unsigned short, h);
    ws[idx] = hb;
    ws[65536 + j*256 + i] = hb;
}

__device__ __forceinline__ float fast_tanh(float x)
{
    float e = __expf(2.0f * x);
    return 1.0f - __fdividef(2.0f, e + 1.0f);
}

// ---------------------------------------------------------------------------
// 512 threads = 8 waves; block owns 32 batch rows. Waves 0-3: Xv 64-feat
// strips; waves 4-7: Xh.
// launch_bounds(512,4): cap 128 regs/wave -> 16 waves/CU = 2 blocks/CU, so
// one block's tanh (VALU) overlaps the other's MFMA (separate pipes, m114).
// A-operand (W, L2-resident 1 MB) streamed via 2-deep register pipeline:
// a0=frags(kt), a1=frags(kt+1), prefetch (kt+2)&7 each step — W is
// iteration-invariant so the pipeline wraps across iterations seamlessly.
// g (fp16) double-buffered in LDS (2 x 32 KiB) -> ONE barrier per iteration.
// Race-free: phase1(it+1) writes buf[(it+1)&1]; slowest wave in phase2(it)
// reads buf[it&1]. Swizzle: XOR (li<<4) on full byte offset (bijective per
// 512B row; preserves 8B/16B alignment; residual 2-way conflict free, m136).
// ---------------------------------------------------------------------------

__launch_bounds__(512, 4)
__global__ void HAM_main(const float* __restrict__ xv_in, const float* __restrict__ xh_in,
                         const unsigned short* __restrict__ wsp, const int* __restrict__ miter,
                         float* __restrict__ out)
{
    extern __shared__ char smem[];   // 64 KiB: buf0{gv|gh} buf1{gv|gh}, 16 KiB halves
    const int tid  = threadIdx.x;
    const int wid  = tid >> 6;
    const int lane = tid & 63;
    const int li   = lane & 15;      // MFMA m/n index within tile
    const int g    = lane >> 4;      // quarter-wave group (k-chunk)
    const bool isV = (wid < 4);
    const int fbase = (wid & 3) * 64;
    const long b0 = (long)blockIdx.x * 32;

    const float* xin = isV ? xv_in : xh_in;
    const unsigned short* aP = wsp + (isV ? 0 : 65536);
    const int wrHalf = isV ? 0 : 16384;      // my g goes here (within a buffer)
    const int rdHalf = isV ? 16384 : 0;      // my GEMM consumes the other half

    // per-mt base pointers for A fragments; chunk kt at byte offset kt*64
    const unsigned short* aRow[4];
    #pragma unroll
    for (int mt = 0; mt < 4; ++mt)
        aRow[mt] = aP + (fbase + mt*16 + li)*256 + g*8;

    // ---- load initial state into accumulators (D-layout) ----
    f32x4 acc[4][2];
    #pragma unroll
    for (int mt = 0; mt < 4; ++mt)
        #pragma unroll
        for (int nt = 0; nt < 2; ++nt) {
            long b = b0 + nt*16 + li;
            int  f = fbase + mt*16 + g*4;
            acc[mt][nt] = *(const f32x4*)(xin + b*256 + f);
        }

    // ---- prime the A pipeline: kt=0 -> a0, kt=1 -> a1 ----
    f16x8 a0[4], a1[4];
    #pragma unroll
    for (int mt = 0; mt < 4; ++mt) {
        a0[mt] = *(const f16x8*)(aRow[mt]);
        a1[mt] = *(const f16x8*)(aRow[mt] + 32);
    }

    const int iters = *miter;

    for (int it = 0; it < iters; ++it) {
        char* buf = smem + (it & 1) * 32768;
        char* wr  = buf + wrHalf;
        char* rd  = buf + rdHalf;

        // ---- phase 1: g = tanh(x) -> fp16 pairs (cvt_pkrtz) -> LDS ----
        #pragma unroll
        for (int mt = 0; mt < 4; ++mt) {
            #pragma unroll
            for (int nt = 0; nt < 2; ++nt) {
                float t0 = fast_tanh(acc[mt][nt][0]);
                float t1 = fast_tanh(acc[mt][nt][1]);
                float t2 = fast_tanh(acc[mt][nt][2]);
                float t3 = fast_tanh(acc[mt][nt][3]);
                uint32 u01 = __builtin_bit_cast(uint32, __builtin_amdgcn_cvt_pkrtz(t0, t1));
                uint32 u23 = __builtin_bit_cast(uint32, __builtin_amdgcn_cvt_pkrtz(t2, t3));
                int off = (((nt*16 + li) * 512) + (fbase + mt*16 + g*4) * 2) ^ (li << 4);
                *(uint2*)(wr + off) = make_uint2(u01, u23);
            }
        }
        __syncthreads();

        // ---- phase 2: x_new = 0.5*x + g_other * (0.5*W) ----
        #pragma unroll
        for (int mt = 0; mt < 4; ++mt)
            #pragma unroll
            for (int nt = 0; nt < 2; ++nt)
                acc[mt][nt] *= 0.5f;

        #pragma unroll
        for (int kt = 0; kt < 8; ++kt) {
            #pragma unroll
            for (int nt = 0; nt < 2; ++nt) {
                int off = (((nt*16 + li) * 512) + kt*64 + g*16) ^ (li << 4);
                f16x8 bH = *(const f16x8*)(rd + off);
                #pragma unroll
                for (int mt = 0; mt < 4; ++mt)
                    acc[mt][nt] = __builtin_amdgcn_mfma_f32_16x16x32_f16(a0[mt], bH, acc[mt][nt], 0, 0, 0);
            }
            // rotate pipeline: a0 <- a1, prefetch chunk (kt+2)&7 into a1
            #pragma unroll
            for (int mt = 0; mt < 4; ++mt) {
                a0[mt] = a1[mt];
                a1[mt] = *(const f16x8*)(aRow[mt] + ((kt + 2) & 7) * 32);
            }
        }
        // no trailing barrier: next phase-1 writes the OTHER buffer
    }

    // ---- epilogue: out[b] = [tanh(xv), tanh(xh)] ----
    const int colBase = (isV ? 0 : 256) + fbase;
    #pragma unroll
    for (int mt = 0; mt < 4; ++mt) {
        #pragma unroll
        for (int nt = 0; nt < 2; ++nt) {
            long b = b0 + nt*16 + li;
            f32x4 o;
            #pragma unroll
            for (int j = 0; j < 4; ++j) o[j] = fast_tanh(acc[mt][nt][j]);
            *(f32x4*)(out + b*512 + colBase + mt*16 + g*4) = o;
        }
    }
}

extern "C" void kernel_launch(void* const* d_in, const int* in_sizes, int n_in,
                              void* d_out, int out_size, void* d_ws, size_t ws_size,
                              hipStream_t stream)
{
    const float* xv   = (const float*)d_in[0];
    const float* xh   = (const float*)d_in[1];
    const float* W    = (const float*)d_in[2];
    const int* miter  = (const int*)d_in[3];
    float* out        = (float*)d_out;
    unsigned short* ws = (unsigned short*)d_ws;

    const int B = in_sizes[0] / 256;        // 32768

    HAM_prep_w<<<256, 256, 0, stream>>>(W, ws);

    (void)hipFuncSetAttribute((const void*)HAM_main,
                              hipFuncAttributeMaxDynamicSharedMemorySize, 65536);
    HAM_main<<<B / 32, 512, 65536, stream>>>(xv, xh, ws, miter, out);
}

// Round 8
// 165.208 us; speedup vs baseline: 1.9037x; 1.9037x over previous
//
#include <hip/hip_runtime.h>
#include <cstdint>

typedef float    f32x4 __attribute__((ext_vector_type(4)));
typedef _Float16 f16x8 __attribute__((ext_vector_type(8)));
typedef unsigned int uint32;

// ---------------------------------------------------------------------------
// Workspace (ushort units): two fp16[256][256] arrays (RNE, alpha folded in)
//   [0]      Wn[i][j] = f16(0.5*W[i][j])   (A-operand for Xv update)
//   [65536]  Wt[j][i] = f16(0.5*W[i][j])   (A-operand for Xh update)
// ---------------------------------------------------------------------------

__global__ void HAM_prep_w(const float* __restrict__ W, unsigned short* __restrict__ ws)
{
    int idx = blockIdx.x * 256 + threadIdx.x;          // 0 .. 65535
    int i = idx >> 8, j = idx & 255;
    _Float16 h = (_Float16)(0.5f * W[idx]);            // RNE, rel err <= 2^-12
    unsigned short hb = __builtin_bit_cast(unsigned short, h);
    ws[idx] = hb;
    ws[65536 + j*256 + i] = hb;
}

__device__ __forceinline__ float fast_tanh(float x)
{
    float e = __expf(2.0f * x);
    return 1.0f - __fdividef(2.0f, e + 1.0f);
}

// ---------------------------------------------------------------------------
// 1024 threads = 16 waves; block owns 32 batch rows.
// Waves 0-7: Xv, 32-feature strip each (8 x 32 = all 256 features).
// Waves 8-15: Xh likewise.
// Per-wave register budget (pinned via waves_per_eu(4,4) => 128 regs):
//   aW[2][8] = 64 (W strip, resident ALL iterations - zero global loads in
//   the loop), acc[2][2] = 16, temps ~30  =>  ~110 <= 128, no spill.
// 4 waves/SIMD TLP hides LDS latency; g double-buffered (2 x 32 KiB),
// ONE barrier/iter: phase1 writes buf[it&1], barrier, phase2 reads it;
// next phase1 writes buf[(it+1)&1] - race-free vs stragglers.
// Swizzle: XOR (li<<4) on the full byte offset (bijective per 512 B row,
// preserves 8/16 B alignment; residual 2-way conflict is free, m136).
// ---------------------------------------------------------------------------

__attribute__((amdgpu_waves_per_eu(4, 4)))
__launch_bounds__(1024)
__global__ void HAM_main(const float* __restrict__ xv_in, const float* __restrict__ xh_in,
                         const unsigned short* __restrict__ wsp, const int* __restrict__ miter,
                         float* __restrict__ out)
{
    extern __shared__ char smem[];   // 64 KiB: buf0{gv|gh} buf1{gv|gh}, 16 KiB halves
    const int tid  = threadIdx.x;
    const int wid  = tid >> 6;
    const int lane = tid & 63;
    const int li   = lane & 15;      // MFMA m/n index within tile
    const int g    = lane >> 4;      // quarter-wave group (k-chunk)
    const bool isV = (wid < 8);
    const int fbase = (wid & 7) * 32;
    const long b0 = (long)blockIdx.x * 32;

    const float* xin = isV ? xv_in : xh_in;
    const unsigned short* aP = wsp + (isV ? 0 : 65536);
    const int wrHalf = isV ? 0 : 16384;      // my g goes here (within a buffer)
    const int rdHalf = isV ? 16384 : 0;      // my GEMM consumes the other half

    // ---- preload W strip into registers: aW[2][8] = 64 VGPRs, all iters ----
    f16x8 aW[2][8];
    #pragma unroll
    for (int mt = 0; mt < 2; ++mt) {
        const unsigned short* rp = aP + (fbase + mt*16 + li)*256 + g*8;
        #pragma unroll
        for (int kt = 0; kt < 8; ++kt)
            aW[mt][kt] = *(const f16x8*)(rp + kt*32);   // ushort-unit offsets
    }

    // ---- load initial state into accumulators (D-layout) ----
    f32x4 acc[2][2];
    #pragma unroll
    for (int mt = 0; mt < 2; ++mt)
        #pragma unroll
        for (int nt = 0; nt < 2; ++nt) {
            long b = b0 + nt*16 + li;
            int  f = fbase + mt*16 + g*4;
            acc[mt][nt] = *(const f32x4*)(xin + b*256 + f);
        }

    const int iters = *miter;

    for (int it = 0; it < iters; ++it) {
        char* buf = smem + (it & 1) * 32768;
        char* wr  = buf + wrHalf;
        char* rd  = buf + rdHalf;

        // ---- phase 1: g = tanh(x) -> fp16 pairs (cvt_pkrtz) -> LDS ----
        #pragma unroll
        for (int mt = 0; mt < 2; ++mt) {
            #pragma unroll
            for (int nt = 0; nt < 2; ++nt) {
                float t0 = fast_tanh(acc[mt][nt][0]);
                float t1 = fast_tanh(acc[mt][nt][1]);
                float t2 = fast_tanh(acc[mt][nt][2]);
                float t3 = fast_tanh(acc[mt][nt][3]);
                uint32 u01 = __builtin_bit_cast(uint32, __builtin_amdgcn_cvt_pkrtz(t0, t1));
                uint32 u23 = __builtin_bit_cast(uint32, __builtin_amdgcn_cvt_pkrtz(t2, t3));
                int off = (((nt*16 + li) * 512) + (fbase + mt*16 + g*4) * 2) ^ (li << 4);
                *(uint2*)(wr + off) = make_uint2(u01, u23);
            }
        }
        __syncthreads();

        // ---- phase 2: x_new = 0.5*x + g_other * (0.5*W) ----
        #pragma unroll
        for (int mt = 0; mt < 2; ++mt)
            #pragma unroll
            for (int nt = 0; nt < 2; ++nt)
                acc[mt][nt] *= 0.5f;

        #pragma unroll
        for (int kt = 0; kt < 8; ++kt) {
            #pragma unroll
            for (int nt = 0; nt < 2; ++nt) {
                int off = (((nt*16 + li) * 512) + kt*64 + g*16) ^ (li << 4);
                f16x8 bH = *(const f16x8*)(rd + off);
                #pragma unroll
                for (int mt = 0; mt < 2; ++mt)
                    acc[mt][nt] = __builtin_amdgcn_mfma_f32_16x16x32_f16(aW[mt][kt], bH, acc[mt][nt], 0, 0, 0);
            }
        }
        // no trailing barrier: next phase-1 writes the OTHER buffer
    }

    // ---- epilogue: out[b] = [tanh(xv), tanh(xh)] ----
    const int colBase = (isV ? 0 : 256) + fbase;
    #pragma unroll
    for (int mt = 0; mt < 2; ++mt) {
        #pragma unroll
        for (int nt = 0; nt < 2; ++nt) {
            long b = b0 + nt*16 + li;
            f32x4 o;
            #pragma unroll
            for (int j = 0; j < 4; ++j) o[j] = fast_tanh(acc[mt][nt][j]);
            *(f32x4*)(out + b*512 + colBase + mt*16 + g*4) = o;
        }
    }
}

extern "C" void kernel_launch(void* const* d_in, const int* in_sizes, int n_in,
                              void* d_out, int out_size, void* d_ws, size_t ws_size,
                              hipStream_t stream)
{
    const float* xv   = (const float*)d_in[0];
    const float* xh   = (const float*)d_in[1];
    const float* W    = (const float*)d_in[2];
    const int* miter  = (const int*)d_in[3];
    float* out        = (float*)d_out;
    unsigned short* ws = (unsigned short*)d_ws;

    const int B = in_sizes[0] / 256;        // 32768

    HAM_prep_w<<<256, 256, 0, stream>>>(W, ws);

    (void)hipFuncSetAttribute((const void*)HAM_main,
                              hipFuncAttributeMaxDynamicSharedMemorySize, 65536);
    HAM_main<<<B / 32, 1024, 65536, stream>>>(xv, xh, ws, miter, out);
}